// Round 8
// baseline (166.461 us; speedup 1.0000x reference)
//
#include <hip/hip_runtime.h>
#include <cstdint>
#include <cstddef>

#define HW 25600

typedef __attribute__((ext_vector_type(8))) short bf16x8;
typedef __attribute__((ext_vector_type(16))) float f32x16;

union ABu { bf16x8 v; uint2 u[2]; };
union B128 { bf16x8 v; int4 q; };

__device__ __forceinline__ f32x16 zero16() {
    f32x16 z;
#pragma unroll
    for (int i = 0; i < 16; ++i) z[i] = 0.f;
    return z;
}

__device__ __forceinline__ unsigned short f2bf(float x) {
    unsigned u = __builtin_bit_cast(unsigned, x);
    unsigned r = (u + 0x7FFF + ((u >> 16) & 1)) >> 16;
    return (unsigned short)r;
}

__device__ __forceinline__ float bf2f(unsigned short s) {
    return __builtin_bit_cast(float, (unsigned)s << 16);
}

__device__ __forceinline__ float wred(float v) {
#pragma unroll
    for (int off = 32; off; off >>= 1) v += __shfl_down(v, off, 64);
    return v;
}

__device__ double blockReduce256D(double v, double* s4) {
#pragma unroll
    for (int off = 32; off; off >>= 1) v += __shfl_down(v, off, 64);
    __syncthreads();
    if ((threadIdx.x & 63) == 0) s4[threadIdx.x >> 6] = v;
    __syncthreads();
    return s4[0] + s4[1] + s4[2] + s4[3];
}

// ---------- K1: softmax / gather / weights + cnt,E partials ----------
__global__ __launch_bounds__(256) void k1_prep(
    const float* __restrict__ PredS, const float* __restrict__ PredT,
    const int* __restrict__ target,
    int* __restrict__ cls_arr, float* __restrict__ wT_arr,
    float* __restrict__ w_arr, float* __restrict__ partial_prep)
{
    __shared__ float sL[4][20];
    int blk = blockIdx.x;
    int b = blk / 100, r = blk - b * 100;
    int t = threadIdx.x, w = t >> 6, lane = t & 63;
    int ql = r * 256 + t;
    int v = ((t >> 4) * 160) + ((t & 15) * 16) + ((r >> 4) * 2560) + (r & 15);

    int cls = target[b * HW + v];

    const float* pS = PredS + b * 4 * HW + v;
    float a0 = pS[0], a1 = pS[HW], a2 = pS[2 * HW], a3 = pS[3 * HW];
    float mS = fmaxf(fmaxf(a0, a1), fmaxf(a2, a3));
    float e0 = expf(a0 - mS), e1 = expf(a1 - mS), e2 = expf(a2 - mS), e3 = expf(a3 - mS);
    float invS = 1.0f / (e0 + e1 + e2 + e3);
    float wei_s = ((cls == 0) ? e0 : (cls == 1) ? e1 : (cls == 2) ? e2 : e3) * invS;

    const float* pT = PredT + b * 4 * HW + v;
    float c0 = pT[0], c1 = pT[HW], c2 = pT[2 * HW], c3 = pT[3 * HW];
    float mT = fmaxf(fmaxf(c0, c1), fmaxf(c2, c3));
    float f0 = expf(c0 - mT), f1 = expf(c1 - mT), f2 = expf(c2 - mT), f3 = expf(c3 - mT);
    float invT = 1.0f / (f0 + f1 + f2 + f3);
    float tn0 = f0 * invT, tn1 = f1 * invT, tn2 = f2 * invT, tn3 = f3 * invT;
    float wei_t = (cls == 0) ? tn0 : (cls == 1) ? tn1 : (cls == 2) ? tn2 : tn3;

    cls_arr[b * HW + ql] = cls;
    wT_arr[b * HW + ql] = wei_t;
    w_arr[b * HW + ql] = (1.0f - wei_s) * wei_t;

    float vals[20];
#pragma unroll
    for (int s = 0; s < 4; ++s) vals[s] = (cls == s) ? 1.f : 0.f;
#pragma unroll
    for (int i2 = 0; i2 < 4; ++i2) {
        vals[4 + i2 * 4 + 0] = (cls == i2) ? tn0 : 0.f;
        vals[4 + i2 * 4 + 1] = (cls == i2) ? tn1 : 0.f;
        vals[4 + i2 * 4 + 2] = (cls == i2) ? tn2 : 0.f;
        vals[4 + i2 * 4 + 3] = (cls == i2) ? tn3 : 0.f;
    }
#pragma unroll
    for (int s = 0; s < 20; ++s) {
        float rv = wred(vals[s]);
        if (lane == 0) sL[w][s] = rv;
    }
    __syncthreads();
    if (t < 20) {
        int ob = blk * 20;
        partial_prep[ob + t] = sL[0][t] + sL[1][t] + sL[2][t] + sL[3][t];
    }
}

// ---------- K2: W matrices -> bf16 packed [q][4] ; blocks >=1024 do the cnt/E reduce ----------
__global__ __launch_bounds__(128) void k2_w(
    const float* __restrict__ Satt, const float* __restrict__ Tatt,
    const int* __restrict__ cls_arr, const float* __restrict__ wT_arr,
    unsigned short* __restrict__ Wbf_S, unsigned short* __restrict__ Wbf_T,
    const float* __restrict__ partial_prep, float* __restrict__ cnt, float* __restrict__ E)
{
    int blk = blockIdx.x;
    int t = threadIdx.x;
    if (blk >= 1024) {
        int i = blk - 1024;  // 0..79
        if (t < 64) {
            int b = i / 20, s = i - (i / 20) * 20;
            float a = partial_prep[(b * 100 + t) * 20 + s];
            if (t + 64 < 100) a += partial_prep[(b * 100 + t + 64) * 20 + s];
            a = wred(a);
            if (t == 0) { if (s < 4) cnt[b * 4 + s] = a; else E[b * 16 + (s - 4)] = a; }
        }
        return;
    }
    __shared__ float Al[100 * 101];
    __shared__ int cls_s[100];
    __shared__ float wTs[100];
    int b = blk >> 8, i = blk & 255;
    if (t < 100) {
        cls_s[t] = cls_arr[b * HW + i * 100 + t];
        wTs[t] = wT_arr[b * HW + i * 100 + t];
    }
    for (int f = t; f < 10000; f += 128) Al[f + f / 100] = Satt[b * 10000 + f];
    __syncthreads();
    if (t < 100) {
        float a0 = 0, a1 = 0, a2 = 0, a3 = 0;
        for (int jc = 0; jc < 100; ++jc) {
            float a = Al[t * 101 + jc];
            int cc = cls_s[jc];
            a0 += (cc == 0) ? a : 0.f;
            a1 += (cc == 1) ? a : 0.f;
            a2 += (cc == 2) ? a : 0.f;
            a3 += (cc == 3) ? a : 0.f;
        }
        uint2 pk;
        pk.x = (unsigned)f2bf(a0) | ((unsigned)f2bf(a1) << 16);
        pk.y = (unsigned)f2bf(a2) | ((unsigned)f2bf(a3) << 16);
        *(uint2*)(Wbf_S + (size_t)(b * HW + i * 100 + t) * 4) = pk;
    }
    __syncthreads();
    for (int f = t; f < 10000; f += 128) Al[f + f / 100] = Tatt[b * 10000 + f];
    __syncthreads();
    if (t < 100) {
        float a0 = 0, a1 = 0, a2 = 0, a3 = 0;
        for (int jc = 0; jc < 100; ++jc) {
            float a = Al[t * 101 + jc] * wTs[jc];
            int cc = cls_s[jc];
            a0 += (cc == 0) ? a : 0.f;
            a1 += (cc == 1) ? a : 0.f;
            a2 += (cc == 2) ? a : 0.f;
            a3 += (cc == 3) ? a : 0.f;
        }
        uint2 pk;
        pk.x = (unsigned)f2bf(a0) | ((unsigned)f2bf(a1) << 16);
        pk.y = (unsigned)f2bf(a2) | ((unsigned)f2bf(a3) << 16);
        *(uint2*)(Wbf_T + (size_t)(b * HW + i * 100 + t) * 4) = pk;
    }
}

// ---------- K3 v6: lean DMA-staged permute + Sum ----------
// grid 14336: x = side*7168 + (b*7+D)*256 + c. One c per block.
// Stage 16 rows x 256 f32 via global_load_lds with XOR-pre-swizzled source
// (lane ^ (A&7)); read with the same XOR; store bf16 featP via v_cvt_pk_bf16_f32.
// Mapping (verified): thread t, rep, e -> q = D*4096 + rep*2048 + 8t + e,
// column o = 128(t&1) + 16e + 8rep + (t>>5), row A = (t&31)>>1.
__global__ __launch_bounds__(256) void k3_scan(
    const float* __restrict__ featS, const float* __restrict__ featT,
    const unsigned short* __restrict__ WbfS, const unsigned short* __restrict__ WbfT,
    unsigned short* __restrict__ featP, float* __restrict__ pp)
{
    __shared__ __align__(16) float fL[16 * 256];
    __shared__ float sL[16];
    int x = blockIdx.x;
    int side = x / 7168;
    int rest = x - side * 7168;
    int c = rest & 255;
    int bd = rest >> 8;
    int D = bd % 7, b = bd / 7;
    int t = threadIdx.x, w = t >> 6, l = t & 63;

    const float* feat = side ? featT : featS;
    const unsigned short* Wbf = side ? WbfT : WbfS;
    unsigned short* fP = featP + (size_t)side * 26214400u;

    const float* fbase = feat + (size_t)(b * 256 + c) * HW + 2560 * D;
    // DMA staging: wave w stages rows A = w, w+4, w+8, w+12; source pre-swizzled
#pragma unroll
    for (int ra = 0; ra < 4; ++ra) {
        int A = w + 4 * ra;
        const float* src = fbase + 160 * A + ((l ^ (A & 7)) << 2);
        __builtin_amdgcn_global_load_lds(
            (const __attribute__((address_space(1))) void*)src,
            (__attribute__((address_space(3))) void*)(fL + A * 256),
            16, 0, 0);
    }

    int nr = (D < 6) ? 2 : 1;
    bool act = !(D == 6 && t >= 128);
    // W fragments: issue before barrier so latency overlaps the DMA drain
    int4 w4[2][4];
#pragma unroll
    for (int rep = 0; rep < 2; ++rep) {
        if (rep < nr && act) {
            int Pb = D * 4096 + rep * 2048 + t * 8;
            const int4* wp = (const int4*)(Wbf + ((size_t)b * HW + Pb) * 4);
            w4[rep][0] = wp[0]; w4[rep][1] = wp[1]; w4[rep][2] = wp[2]; w4[rep][3] = wp[3];
        }
    }

    __syncthreads();

    float as0 = 0.f, as1 = 0.f, as2 = 0.f, as3 = 0.f;
    int A2 = (t & 31) >> 1;
    int rowb = A2 * 256;
    int sw = A2 & 7;
    int obase = 128 * (t & 1) + (t >> 5);
    if (act) {
#pragma unroll
        for (int rep = 0; rep < 2; ++rep) {
            if (rep < nr) {
                float fv[8];
#pragma unroll
                for (int e = 0; e < 8; ++e) {
                    int o = obase + 8 * rep + 16 * e;
                    fv[e] = fL[rowb + (((o >> 2) ^ sw) << 2) + (o & 3)];
                }
                const unsigned short* ww = (const unsigned short*)w4[rep];
#pragma unroll
                for (int e = 0; e < 8; ++e) {
                    as0 += fv[e] * bf2f(ww[e * 4 + 0]);
                    as1 += fv[e] * bf2f(ww[e * 4 + 1]);
                    as2 += fv[e] * bf2f(ww[e * 4 + 2]);
                    as3 += fv[e] * bf2f(ww[e * 4 + 3]);
                }
                int4 outp;
#pragma unroll
                for (int pr = 0; pr < 4; ++pr) {
                    unsigned rr;
                    asm("v_cvt_pk_bf16_f32 %0, %1, %2"
                        : "=v"(rr) : "v"(fv[2 * pr]), "v"(fv[2 * pr + 1]));
                    ((unsigned*)&outp)[pr] = rr;
                }
                *(int4*)(fP + (size_t)(b * 256 + c) * HW + D * 4096 + rep * 2048 + t * 8) = outp;
            }
        }
    }

    float rv0 = wred(as0), rv1 = wred(as1), rv2 = wred(as2), rv3 = wred(as3);
    if (l == 0) {
        sL[w * 4 + 0] = rv0; sL[w * 4 + 1] = rv1;
        sL[w * 4 + 2] = rv2; sL[w * 4 + 3] = rv3;
    }
    __syncthreads();
    if (t < 4) {
        pp[side * 28672 + ((b * 7 + D) * 256 + c) * 4 + t] =
            sL[t] + sL[4 + t] + sL[8 + t] + sL[12 + t];
    }
}

// ---------- K3.5: reduce 7 D-partials (both sides) ----------
__global__ void k35_red(const float* __restrict__ pp, float* __restrict__ SumAll)
{
    int id = blockIdx.x * 256 + threadIdx.x;  // 8192
    int side = id >> 12;
    int rem = id & 4095;
    int bc = rem >> 2, j = rem & 3;
    int b = bc >> 8, c = bc & 255;
    float a = 0.f;
    for (int D = 0; D < 7; ++D)
        a += pp[side * 28672 + (((b * 7 + D) * 256) + c) * 4 + j];
    SumAll[side * 4096 + bc * 4 + j] = a;
}

// ---------- K4 v2: both sides, B fragments in registers ----------
__global__ __launch_bounds__(256, 2) void k4_mfma(
    const unsigned short* __restrict__ featP,
    const float* __restrict__ SattG, const float* __restrict__ TattG,
    const float* __restrict__ SumAll,
    float* __restrict__ n2S, float* __restrict__ n2T,
    float* __restrict__ dotS, float* __restrict__ dotT)
{
    __shared__ __align__(16) unsigned short featL[32 * 408 + 16];
    __shared__ __align__(16) unsigned short attL[100 * 136];

    int x = blockIdx.x;
    int side = x & 1, chalf = (x >> 1) & 1, b = (x >> 2) & 3, g = x >> 4;
    int t = threadIdx.x, w = t >> 6, l = t & 63;

    const float* Att = side ? TattG : SattG;
    const float* Sum = SumAll + side * 4096;
    const unsigned short* fP = featP + (size_t)side * 26214400u;
    float* n2h = side ? n2T : n2S;
    float* doth = side ? dotT : dotS;

    for (int f = t; f < 13600; f += 256) attL[f] = 0;
    featL[(t >> 3) * 408 + 400 + (t & 7)] = 0;
    if (t < 16) featL[32 * 408 + t] = 0;
    __syncthreads();
    for (int f = t; f < 10000; f += 256) {
        int k = f / 100, j = f - k * 100;
        attL[j * 136 + k] = f2bf(Att[b * 10000 + f]);
    }
    __syncthreads();

    int lj = l & 31, lh = l >> 5;
    bf16x8 breg[7][4];
    {
        int j3 = 96 + lj; if (j3 > 99) j3 = 99;
        int rowoff[4] = { lj, 32 + lj, 64 + lj, j3 };
#pragma unroll
        for (int ks = 0; ks < 7; ++ks)
#pragma unroll
            for (int s = 0; s < 4; ++s)
                breg[ks][s] = ((const B128*)(attL + rowoff[s] * 136 + lh * 8 + ks * 16))->v;
    }

    float n2a[4] = {0, 0, 0, 0};
    float dota[4][4] = {};
    const unsigned short* arow = featL + lj * 408 + w * 100 + lh * 8;

#pragma unroll 1
    for (int ch = 0; ch < 4; ++ch) {
        __syncthreads();
        {
            const unsigned short* src = fP + (size_t)(b * 256 + chalf * 128 + ch * 32 + (t >> 3)) * HW
                                        + g * 400 + (t & 7) * 8;
            unsigned short* dst = featL + (t >> 3) * 408 + (t & 7) * 8;
#pragma unroll
            for (int i = 0; i < 7; ++i) {
                int cb = (t & 7) + i * 8;
                if (cb < 50)
                    *(int4*)(dst + i * 64) = *(const int4*)(src + i * 64);
            }
        }
        __syncthreads();

        f32x16 acc0 = zero16(), acc1 = zero16(), acc2 = zero16(), acc3 = zero16();
#pragma unroll
        for (int ks = 0; ks < 7; ++ks) {
            ABu aF;
            aF.u[0] = *(const uint2*)(arow + ks * 16);
            aF.u[1] = *(const uint2*)(arow + ks * 16 + 4);
            acc0 = __builtin_amdgcn_mfma_f32_32x32x16_bf16(aF.v, breg[ks][0], acc0, 0, 0, 0);
            acc1 = __builtin_amdgcn_mfma_f32_32x32x16_bf16(aF.v, breg[ks][1], acc1, 0, 0, 0);
            acc2 = __builtin_amdgcn_mfma_f32_32x32x16_bf16(aF.v, breg[ks][2], acc2, 0, 0, 0);
            acc3 = __builtin_amdgcn_mfma_f32_32x32x16_bf16(aF.v, breg[ks][3], acc3, 0, 0, 0);
        }

        int cb0 = chalf * 128 + ch * 32 + (lh << 2);
#pragma unroll
        for (int r = 0; r < 16; ++r) {
            int cl = (r & 3) + ((r >> 2) << 3);
            float4 sv = *(const float4*)(Sum + (size_t)(b * 256 + cb0 + cl) * 4);
            float v;
            v = acc0[r]; n2a[0] += v * v;
            dota[0][0] += v * sv.x; dota[0][1] += v * sv.y; dota[0][2] += v * sv.z; dota[0][3] += v * sv.w;
            v = acc1[r]; n2a[1] += v * v;
            dota[1][0] += v * sv.x; dota[1][1] += v * sv.y; dota[1][2] += v * sv.z; dota[1][3] += v * sv.w;
            v = acc2[r]; n2a[2] += v * v;
            dota[2][0] += v * sv.x; dota[2][1] += v * sv.y; dota[2][2] += v * sv.z; dota[2][3] += v * sv.w;
            v = acc3[r]; n2a[3] += v * v;
            dota[3][0] += v * sv.x; dota[3][1] += v * sv.y; dota[3][2] += v * sv.z; dota[3][3] += v * sv.w;
        }
    }

#pragma unroll
    for (int nt = 0; nt < 4; ++nt) {
        n2a[nt] += __shfl_down(n2a[nt], 32, 64);
#pragma unroll
        for (int m = 0; m < 4; ++m) dota[nt][m] += __shfl_down(dota[nt][m], 32, 64);
    }
    if (l < 32) {
        int i0 = g * 4 + w;
        int pqb = b * HW + i0 * 100;
#pragma unroll
        for (int nt = 0; nt < 4; ++nt) {
            int j = nt * 32 + l;
            if (j < 100) {
                n2h[chalf * 102400 + pqb + j] = n2a[nt];
                float4 dv = {dota[nt][0], dota[nt][1], dota[nt][2], dota[nt][3]};
                *(float4*)(doth + chalf * 409600 + (size_t)(pqb + j) * 4) = dv;
            }
        }
    }
}

// ---------- K4.5: per-batch tables (parallel colnorms) ----------
__global__ void k45_tbl(const float* __restrict__ SumTS, const float* __restrict__ SumTT,
                        const float* __restrict__ cnt, const float* __restrict__ E,
                        float* __restrict__ tbl)
{
    int blk = blockIdx.x, t = threadIdx.x;
    if (blk < 32) {
        int b = blk >> 3, sj = blk & 7, stv = sj >> 2, j = sj & 3;
        const float* S = stv ? SumTT : SumTS;
        float s = 0.f;
#pragma unroll
        for (int u = 0; u < 4; ++u) {
            float xx = S[(b * 256 + t * 4 + u) * 4 + j];
            s += xx * xx;
        }
        s = wred(s);
        if (t == 0) tbl[b * 32 + stv * 4 + j] = sqrtf(s);
    } else if (t < 16) {
        int b = t >> 2, i = t & 3;
        tbl[b * 32 + 8 + 0 * 4 + i] = cnt[b * 4 + i] + 1e-6f;
        tbl[b * 32 + 8 + 1 * 4 + i] = cnt[b * 4 + (i ^ 2)] + 1e-6f;
        tbl[b * 32 + 8 + 2 * 4 + i] = cnt[b * 4 + (i ^ 3)] + 1.0f;
        tbl[b * 32 + 20 + 0 * 4 + i] = E[b * 16 + i * 4 + (i ^ 1)] + 1e-6f;
        tbl[b * 32 + 20 + 1 * 4 + i] = E[b * 16 + 5 * (i ^ 2)] + 1e-6f;
        tbl[b * 32 + 20 + 2 * 4 + i] = E[b * 16 + 5 * (i ^ 3)] + 1.0f;
    }
}

// ---------- K5: cosines + squared diff ----------
__global__ __launch_bounds__(256) void k5_final(
    const int* __restrict__ cls_arr, const float* __restrict__ w_arr,
    const float* __restrict__ n2S, const float* __restrict__ n2T,
    const float* __restrict__ dotS, const float* __restrict__ dotT,
    const float* __restrict__ tbl, double* __restrict__ partial_res)
{
    __shared__ double s4[4];
    int blk = blockIdx.x;
    int b = blk / 100, r = blk - b * 100;
    int t = threadIdx.x;
    int pq = b * HW + r * 256 + t;

    int i = cls_arr[pq];
    float wv = w_arr[pq];
    float sqS = sqrtf(n2S[pq] + n2S[102400 + pq]);
    float sqT = sqrtf(n2T[pq] + n2T[102400 + pq]);
    float4 dSa = *(const float4*)(dotS + (size_t)pq * 4);
    float4 dSb = *(const float4*)(dotS + 409600 + (size_t)pq * 4);
    float4 dTa = *(const float4*)(dotT + (size_t)pq * 4);
    float4 dTb = *(const float4*)(dotT + 409600 + (size_t)pq * 4);
    float4 dS = {dSa.x + dSb.x, dSa.y + dSb.y, dSa.z + dSb.z, dSa.w + dSb.w};
    float4 dT = {dTa.x + dTb.x, dTa.y + dTb.y, dTa.z + dTb.z, dTa.w + dTb.w};
    const float* tb = tbl + b * 32;

    double acc = 0.0;
#pragma unroll
    for (int v = 0; v < 3; ++v) {
        int j = i ^ (v + 1);
        float dsj = (j == 0) ? dS.x : (j == 1) ? dS.y : (j == 2) ? dS.z : dS.w;
        float dtj = (j == 0) ? dT.x : (j == 1) ? dT.y : (j == 2) ? dT.z : dT.w;
        float cnS = tb[j], cnT = tb[4 + j];
        float denS = tb[8 + v * 4 + i], denT = tb[20 + v * 4 + i];
        float cs = (dsj / denS) / fmaxf(sqS * (cnS / denS), 1e-8f);
        float ct = (dtj / denT) / fmaxf(sqT * (cnT / denT), 1e-8f);
        float vs = wv * cs, vt = wv * ct;
        float d = vs - vt;
        acc += (double)d * (double)d;
    }
    double tot = blockReduce256D(acc, s4);
    if (t == 0) partial_res[blk] = tot;
}

// ---------- K6: parallel final sum ----------
__global__ __launch_bounds__(256) void k6_out(const double* __restrict__ partial_res,
                                              float* __restrict__ out)
{
    __shared__ double s4[4];
    int t = threadIdx.x;
    double v = (t < 200) ? (partial_res[t] + partial_res[t + 200]) : 0.0;
    double tot = blockReduce256D(v, s4);
    if (t == 0) out[0] = (float)(tot / 307200.0);
}

// ---------- launch ----------
extern "C" void kernel_launch(void* const* d_in, const int* in_sizes, int n_in,
                              void* d_out, int out_size, void* d_ws, size_t ws_size,
                              hipStream_t stream)
{
    const float* feat_S  = (const float*)d_in[0];
    const float* feat_T  = (const float*)d_in[1];
    const float* Pred_S  = (const float*)d_in[2];
    const float* Pred_T  = (const float*)d_in[3];
    const float* S_atten = (const float*)d_in[4];
    const float* T_atten = (const float*)d_in[5];
    const int*   target  = (const int*)d_in[6];

    float* ws = (float*)d_ws;
    // non-overlapping layout (float offsets)
    unsigned short* featP = (unsigned short*)d_ws;            // 2 sides x 26,214,400 shorts -> [0, 26214400) floats
    unsigned short* WbfS  = (unsigned short*)(ws + 26214400); // [26214400, 26419200)
    unsigned short* WbfT  = (unsigned short*)(ws + 26419200); // [26419200, 26624000)
    int*   cls_a = (int*)(ws + 26624000);    // [26624000, 26726400)
    float* wT_a  = ws + 26726400;            // [26726400, 26828800)
    float* w_a   = ws + 26828800;            // [26828800, 26931200)
    float* SumTS = ws + 26931200;            // [26931200, 26935296)  (SumAll base)
    float* SumTT = ws + 26935296;            // [26935296, 26939392)
    float* n2S   = ws + 26939392;            // [26939392, 27144192)
    float* n2T   = ws + 27144192;            // [27144192, 27348992)
    float* dotS  = ws + 27348992;            // [27348992, 28168192)
    float* dotT  = ws + 28168192;            // [28168192, 28987392)
    float* pprep = ws + 28987392;            // [28987392, 28995392)
    float* cnt   = ws + 28995392;            // 16
    float* E     = ws + 28995408;            // 64
    float* tbl   = ws + 28995472;            // 128
    double* pres = (double*)(ws + 28995600); // 400 doubles = [28995600, 28996400)
    float* ppart = ws + 28996400;            // 57344 -> ends 29053744 (116.2 MB)

    k1_prep<<<400, 256, 0, stream>>>(Pred_S, Pred_T, target, cls_a, wT_a, w_a, pprep);
    k2_w<<<1104, 128, 0, stream>>>(S_atten, T_atten, cls_a, wT_a, WbfS, WbfT, pprep, cnt, E);
    k3_scan<<<14336, 256, 0, stream>>>(feat_S, feat_T, WbfS, WbfT, featP, ppart);
    k35_red<<<32, 256, 0, stream>>>(ppart, SumTS);
    k4_mfma<<<1024, 256, 0, stream>>>(featP, S_atten, T_atten, SumTS, n2S, n2T, dotS, dotT);
    k45_tbl<<<33, 64, 0, stream>>>(SumTS, SumTT, cnt, E, tbl);
    k5_final<<<400, 256, 0, stream>>>(cls_a, w_a, n2S, n2T, dotS, dotT, tbl, pres);
    k6_out<<<1, 256, 0, stream>>>(pres, (float*)d_out);
}

// Round 9
// 145.563 us; speedup vs baseline: 1.1436x; 1.1436x over previous
//
#include <hip/hip_runtime.h>
#include <cstdint>
#include <cstddef>

#define HW 25600

typedef __attribute__((ext_vector_type(8))) short bf16x8;
typedef __attribute__((ext_vector_type(16))) float f32x16;

union ABu { bf16x8 v; uint2 u[2]; };
union B128 { bf16x8 v; int4 q; };

__device__ __forceinline__ f32x16 zero16() {
    f32x16 z;
#pragma unroll
    for (int i = 0; i < 16; ++i) z[i] = 0.f;
    return z;
}

__device__ __forceinline__ unsigned short f2bf(float x) {
    unsigned u = __builtin_bit_cast(unsigned, x);
    unsigned r = (u + 0x7FFF + ((u >> 16) & 1)) >> 16;
    return (unsigned short)r;
}

__device__ __forceinline__ float bf2f(unsigned short s) {
    return __builtin_bit_cast(float, (unsigned)s << 16);
}

__device__ __forceinline__ float wred(float v) {
#pragma unroll
    for (int off = 32; off; off >>= 1) v += __shfl_down(v, off, 64);
    return v;
}

__device__ double blockReduce256D(double v, double* s4) {
#pragma unroll
    for (int off = 32; off; off >>= 1) v += __shfl_down(v, off, 64);
    __syncthreads();
    if ((threadIdx.x & 63) == 0) s4[threadIdx.x >> 6] = v;
    __syncthreads();
    return s4[0] + s4[1] + s4[2] + s4[3];
}

// ---------- K1: softmax / gather / weights + cnt,E partials ----------
__global__ __launch_bounds__(256) void k1_prep(
    const float* __restrict__ PredS, const float* __restrict__ PredT,
    const int* __restrict__ target,
    int* __restrict__ cls_arr, float* __restrict__ wT_arr,
    float* __restrict__ w_arr, float* __restrict__ partial_prep)
{
    __shared__ float sL[4][20];
    int blk = blockIdx.x;
    int b = blk / 100, r = blk - b * 100;
    int t = threadIdx.x, w = t >> 6, lane = t & 63;
    int ql = r * 256 + t;
    int v = ((t >> 4) * 160) + ((t & 15) * 16) + ((r >> 4) * 2560) + (r & 15);

    int cls = target[b * HW + v];

    const float* pS = PredS + b * 4 * HW + v;
    float a0 = pS[0], a1 = pS[HW], a2 = pS[2 * HW], a3 = pS[3 * HW];
    float mS = fmaxf(fmaxf(a0, a1), fmaxf(a2, a3));
    float e0 = expf(a0 - mS), e1 = expf(a1 - mS), e2 = expf(a2 - mS), e3 = expf(a3 - mS);
    float invS = 1.0f / (e0 + e1 + e2 + e3);
    float wei_s = ((cls == 0) ? e0 : (cls == 1) ? e1 : (cls == 2) ? e2 : e3) * invS;

    const float* pT = PredT + b * 4 * HW + v;
    float c0 = pT[0], c1 = pT[HW], c2 = pT[2 * HW], c3 = pT[3 * HW];
    float mT = fmaxf(fmaxf(c0, c1), fmaxf(c2, c3));
    float f0 = expf(c0 - mT), f1 = expf(c1 - mT), f2 = expf(c2 - mT), f3 = expf(c3 - mT);
    float invT = 1.0f / (f0 + f1 + f2 + f3);
    float tn0 = f0 * invT, tn1 = f1 * invT, tn2 = f2 * invT, tn3 = f3 * invT;
    float wei_t = (cls == 0) ? tn0 : (cls == 1) ? tn1 : (cls == 2) ? tn2 : tn3;

    cls_arr[b * HW + ql] = cls;
    wT_arr[b * HW + ql] = wei_t;
    w_arr[b * HW + ql] = (1.0f - wei_s) * wei_t;

    float vals[20];
#pragma unroll
    for (int s = 0; s < 4; ++s) vals[s] = (cls == s) ? 1.f : 0.f;
#pragma unroll
    for (int i2 = 0; i2 < 4; ++i2) {
        vals[4 + i2 * 4 + 0] = (cls == i2) ? tn0 : 0.f;
        vals[4 + i2 * 4 + 1] = (cls == i2) ? tn1 : 0.f;
        vals[4 + i2 * 4 + 2] = (cls == i2) ? tn2 : 0.f;
        vals[4 + i2 * 4 + 3] = (cls == i2) ? tn3 : 0.f;
    }
#pragma unroll
    for (int s = 0; s < 20; ++s) {
        float rv = wred(vals[s]);
        if (lane == 0) sL[w][s] = rv;
    }
    __syncthreads();
    if (t < 20) {
        int ob = blk * 20;
        partial_prep[ob + t] = sL[0][t] + sL[1][t] + sL[2][t] + sL[3][t];
    }
}

// ---------- K2: W matrices -> bf16 packed [q][4] ; blocks >=1024 do the cnt/E reduce ----------
__global__ __launch_bounds__(128) void k2_w(
    const float* __restrict__ Satt, const float* __restrict__ Tatt,
    const int* __restrict__ cls_arr, const float* __restrict__ wT_arr,
    unsigned short* __restrict__ Wbf_S, unsigned short* __restrict__ Wbf_T,
    const float* __restrict__ partial_prep, float* __restrict__ cnt, float* __restrict__ E)
{
    int blk = blockIdx.x;
    int t = threadIdx.x;
    if (blk >= 1024) {
        int i = blk - 1024;  // 0..79
        if (t < 64) {
            int b = i / 20, s = i - (i / 20) * 20;
            float a = partial_prep[(b * 100 + t) * 20 + s];
            if (t + 64 < 100) a += partial_prep[(b * 100 + t + 64) * 20 + s];
            a = wred(a);
            if (t == 0) { if (s < 4) cnt[b * 4 + s] = a; else E[b * 16 + (s - 4)] = a; }
        }
        return;
    }
    __shared__ float Al[100 * 101];
    __shared__ int cls_s[100];
    __shared__ float wTs[100];
    int b = blk >> 8, i = blk & 255;
    if (t < 100) {
        cls_s[t] = cls_arr[b * HW + i * 100 + t];
        wTs[t] = wT_arr[b * HW + i * 100 + t];
    }
    for (int f = t; f < 10000; f += 128) Al[f + f / 100] = Satt[b * 10000 + f];
    __syncthreads();
    if (t < 100) {
        float a0 = 0, a1 = 0, a2 = 0, a3 = 0;
        for (int jc = 0; jc < 100; ++jc) {
            float a = Al[t * 101 + jc];
            int cc = cls_s[jc];
            a0 += (cc == 0) ? a : 0.f;
            a1 += (cc == 1) ? a : 0.f;
            a2 += (cc == 2) ? a : 0.f;
            a3 += (cc == 3) ? a : 0.f;
        }
        uint2 pk;
        pk.x = (unsigned)f2bf(a0) | ((unsigned)f2bf(a1) << 16);
        pk.y = (unsigned)f2bf(a2) | ((unsigned)f2bf(a3) << 16);
        *(uint2*)(Wbf_S + (size_t)(b * HW + i * 100 + t) * 4) = pk;
    }
    __syncthreads();
    for (int f = t; f < 10000; f += 128) Al[f + f / 100] = Tatt[b * 10000 + f];
    __syncthreads();
    if (t < 100) {
        float a0 = 0, a1 = 0, a2 = 0, a3 = 0;
        for (int jc = 0; jc < 100; ++jc) {
            float a = Al[t * 101 + jc] * wTs[jc];
            int cc = cls_s[jc];
            a0 += (cc == 0) ? a : 0.f;
            a1 += (cc == 1) ? a : 0.f;
            a2 += (cc == 2) ? a : 0.f;
            a3 += (cc == 3) ? a : 0.f;
        }
        uint2 pk;
        pk.x = (unsigned)f2bf(a0) | ((unsigned)f2bf(a1) << 16);
        pk.y = (unsigned)f2bf(a2) | ((unsigned)f2bf(a3) << 16);
        *(uint2*)(Wbf_T + (size_t)(b * HW + i * 100 + t) * 4) = pk;
    }
}

// ---------- K3 (r7-best): double-buffered pipelined permute + Sum ----------
// grid 3584: x = (((b*7+D)*64)+cq)*2 + side; 4 c per block.
__global__ __launch_bounds__(256, 2) void k3_scan(
    const float* __restrict__ featS, const float* __restrict__ featT,
    const unsigned short* __restrict__ WbfS, const unsigned short* __restrict__ WbfT,
    unsigned short* __restrict__ featP, float* __restrict__ pp)
{
    __shared__ unsigned short ldsW[2][16 * 260 + 8];
    __shared__ float sL[16];
    int x = blockIdx.x;
    int side = x & 1;
    int rest = x >> 1;
    int cq = rest & 63;
    int bd = rest >> 6;
    int D = bd % 7, b = bd / 7;
    int t = threadIdx.x, w = t >> 6, lane = t & 63;

    const float* feat = side ? featT : featS;
    const unsigned short* Wbf = side ? WbfT : WbfS;
    unsigned short* fP = featP + (size_t)side * 26214400u;
    int ppbase = side * 28672 + ((b * 7 + D) * 256) * 4;

    int nr = (D < 6) ? 2 : 1;
    bool act = !(D == 6 && t >= 128);

    int4 w4[2][4];
#pragma unroll
    for (int rep = 0; rep < 2; ++rep) {
        if (rep < nr && act) {
            int Pb = D * 4096 + rep * 2048 + t * 8;
            const int4* wp = (const int4*)(Wbf + ((size_t)b * HW + Pb) * 4);
            w4[rep][0] = wp[0]; w4[rep][1] = wp[1]; w4[rep][2] = wp[2]; w4[rep][3] = wp[3];
        }
    }

    const float* fc0 = feat + (size_t)(b * 256 + cq * 4) * HW + 2560 * D;
    int lofs = 4 * (t & 63);

    float4 pf[4];
#pragma unroll
    for (int ra = 0; ra < 4; ++ra)
        pf[ra] = *(const float4*)(fc0 + 160 * ((t >> 6) + 4 * ra) + lofs);

    for (int cv = 0; cv < 4; ++cv) {
        unsigned short* lbuf = ldsW[cv & 1];
#pragma unroll
        for (int ra = 0; ra < 4; ++ra) {
            int A = (t >> 6) + 4 * ra;
            uint2 pk;
            pk.x = (unsigned)f2bf(pf[ra].x) | ((unsigned)f2bf(pf[ra].y) << 16);
            pk.y = (unsigned)f2bf(pf[ra].z) | ((unsigned)f2bf(pf[ra].w) << 16);
            *(uint2*)(lbuf + A * 260 + lofs) = pk;
        }
        __syncthreads();

        if (cv < 3) {
            const float* fcn = fc0 + (size_t)(cv + 1) * HW;
#pragma unroll
            for (int ra = 0; ra < 4; ++ra)
                pf[ra] = *(const float4*)(fcn + 160 * ((t >> 6) + 4 * ra) + lofs);
        }

        int c = cq * 4 + cv;
        float as0 = 0.f, as1 = 0.f, as2 = 0.f, as3 = 0.f;
        if (act) {
#pragma unroll
            for (int rep = 0; rep < 2; ++rep) {
                if (rep < nr) {
                    int Pb = D * 4096 + rep * 2048 + t * 8;
                    int A2 = (t & 31) >> 1;
                    int base_unit = A2 * 260 + 128 * (t & 1) + rep * 8 + (t >> 5);
                    unsigned short us[8];
                    float fv[8];
#pragma unroll
                    for (int e = 0; e < 8; ++e) {
                        us[e] = lbuf[base_unit + 16 * e];
                        fv[e] = bf2f(us[e]);
                    }
                    const unsigned short* ww = (const unsigned short*)w4[rep];
#pragma unroll
                    for (int e = 0; e < 8; ++e) {
                        as0 += fv[e] * bf2f(ww[e * 4 + 0]);
                        as1 += fv[e] * bf2f(ww[e * 4 + 1]);
                        as2 += fv[e] * bf2f(ww[e * 4 + 2]);
                        as3 += fv[e] * bf2f(ww[e * 4 + 3]);
                    }
                    int4 outp;
                    ((unsigned*)&outp)[0] = (unsigned)us[0] | ((unsigned)us[1] << 16);
                    ((unsigned*)&outp)[1] = (unsigned)us[2] | ((unsigned)us[3] << 16);
                    ((unsigned*)&outp)[2] = (unsigned)us[4] | ((unsigned)us[5] << 16);
                    ((unsigned*)&outp)[3] = (unsigned)us[6] | ((unsigned)us[7] << 16);
                    *(int4*)(fP + (size_t)(b * 256 + c) * HW + Pb) = outp;
                }
            }
        }

        float rv0 = wred(as0), rv1 = wred(as1), rv2 = wred(as2), rv3 = wred(as3);
        if (lane == 0) {
            sL[w * 4 + 0] = rv0; sL[w * 4 + 1] = rv1;
            sL[w * 4 + 2] = rv2; sL[w * 4 + 3] = rv3;
        }
        __syncthreads();
        if (t < 4) pp[ppbase + c * 4 + t] = sL[t] + sL[4 + t] + sL[8 + t] + sL[12 + t];
    }
}

// ---------- K4 v3: both sides, B fragments in registers, Sum reduced in-block ----------
__global__ __launch_bounds__(256, 2) void k4_mfma(
    const unsigned short* __restrict__ featP,
    const float* __restrict__ SattG, const float* __restrict__ TattG,
    const float* __restrict__ pp,
    float* __restrict__ n2S, float* __restrict__ n2T,
    float* __restrict__ dotS, float* __restrict__ dotT)
{
    __shared__ __align__(16) unsigned short featL[32 * 408 + 16];
    __shared__ __align__(16) unsigned short attL[100 * 136];
    __shared__ __align__(16) float SumL[128 * 4];

    int x = blockIdx.x;
    int side = x & 1, chalf = (x >> 1) & 1, b = (x >> 2) & 3, g = x >> 4;
    int t = threadIdx.x, w = t >> 6, l = t & 63;

    const float* Att = side ? TattG : SattG;
    const unsigned short* fP = featP + (size_t)side * 26214400u;
    float* n2h = side ? n2T : n2S;
    float* doth = side ? dotT : dotS;

    for (int f = t; f < 13600; f += 256) attL[f] = 0;
    featL[(t >> 3) * 408 + 400 + (t & 7)] = 0;
    if (t < 16) featL[32 * 408 + t] = 0;
    __syncthreads();
    for (int f = t; f < 10000; f += 256) {
        int k = f / 100, j = f - k * 100;
        attL[j * 136 + k] = f2bf(Att[b * 10000 + f]);
    }
    // reduce Sum slice (128 channels x 4 j) from 7 D-partials
#pragma unroll
    for (int f0 = 0; f0 < 2; ++f0) {
        int f = f0 * 256 + t;
        int cl = f >> 2, j = f & 3;
        float s = 0.f;
#pragma unroll
        for (int D = 0; D < 7; ++D)
            s += pp[side * 28672 + ((b * 7 + D) * 256 + chalf * 128 + cl) * 4 + j];
        SumL[f] = s;
    }
    __syncthreads();

    int lj = l & 31, lh = l >> 5;
    bf16x8 breg[7][4];
    {
        int j3 = 96 + lj; if (j3 > 99) j3 = 99;
        int rowoff[4] = { lj, 32 + lj, 64 + lj, j3 };
#pragma unroll
        for (int ks = 0; ks < 7; ++ks)
#pragma unroll
            for (int s = 0; s < 4; ++s)
                breg[ks][s] = ((const B128*)(attL + rowoff[s] * 136 + lh * 8 + ks * 16))->v;
    }

    float n2a[4] = {0, 0, 0, 0};
    float dota[4][4] = {};
    const unsigned short* arow = featL + lj * 408 + w * 100 + lh * 8;

#pragma unroll 1
    for (int ch = 0; ch < 4; ++ch) {
        __syncthreads();
        {
            const unsigned short* src = fP + (size_t)(b * 256 + chalf * 128 + ch * 32 + (t >> 3)) * HW
                                        + g * 400 + (t & 7) * 8;
            unsigned short* dst = featL + (t >> 3) * 408 + (t & 7) * 8;
#pragma unroll
            for (int i = 0; i < 7; ++i) {
                int cb = (t & 7) + i * 8;
                if (cb < 50)
                    *(int4*)(dst + i * 64) = *(const int4*)(src + i * 64);
            }
        }
        __syncthreads();

        f32x16 acc0 = zero16(), acc1 = zero16(), acc2 = zero16(), acc3 = zero16();
#pragma unroll
        for (int ks = 0; ks < 7; ++ks) {
            ABu aF;
            aF.u[0] = *(const uint2*)(arow + ks * 16);
            aF.u[1] = *(const uint2*)(arow + ks * 16 + 4);
            acc0 = __builtin_amdgcn_mfma_f32_32x32x16_bf16(aF.v, breg[ks][0], acc0, 0, 0, 0);
            acc1 = __builtin_amdgcn_mfma_f32_32x32x16_bf16(aF.v, breg[ks][1], acc1, 0, 0, 0);
            acc2 = __builtin_amdgcn_mfma_f32_32x32x16_bf16(aF.v, breg[ks][2], acc2, 0, 0, 0);
            acc3 = __builtin_amdgcn_mfma_f32_32x32x16_bf16(aF.v, breg[ks][3], acc3, 0, 0, 0);
        }

        int cb0 = ch * 32 + (lh << 2);  // channel index within the 128-slice
#pragma unroll
        for (int r = 0; r < 16; ++r) {
            int cl = (r & 3) + ((r >> 2) << 3);
            float4 sv = *(const float4*)(SumL + (size_t)(cb0 + cl) * 4);
            float v;
            v = acc0[r]; n2a[0] += v * v;
            dota[0][0] += v * sv.x; dota[0][1] += v * sv.y; dota[0][2] += v * sv.z; dota[0][3] += v * sv.w;
            v = acc1[r]; n2a[1] += v * v;
            dota[1][0] += v * sv.x; dota[1][1] += v * sv.y; dota[1][2] += v * sv.z; dota[1][3] += v * sv.w;
            v = acc2[r]; n2a[2] += v * v;
            dota[2][0] += v * sv.x; dota[2][1] += v * sv.y; dota[2][2] += v * sv.z; dota[2][3] += v * sv.w;
            v = acc3[r]; n2a[3] += v * v;
            dota[3][0] += v * sv.x; dota[3][1] += v * sv.y; dota[3][2] += v * sv.z; dota[3][3] += v * sv.w;
        }
    }

#pragma unroll
    for (int nt = 0; nt < 4; ++nt) {
        n2a[nt] += __shfl_down(n2a[nt], 32, 64);
#pragma unroll
        for (int m = 0; m < 4; ++m) dota[nt][m] += __shfl_down(dota[nt][m], 32, 64);
    }
    if (l < 32) {
        int i0 = g * 4 + w;
        int pqb = b * HW + i0 * 100;
#pragma unroll
        for (int nt = 0; nt < 4; ++nt) {
            int j = nt * 32 + l;
            if (j < 100) {
                n2h[chalf * 102400 + pqb + j] = n2a[nt];
                float4 dv = {dota[nt][0], dota[nt][1], dota[nt][2], dota[nt][3]};
                *(float4*)(doth + chalf * 409600 + (size_t)(pqb + j) * 4) = dv;
            }
        }
    }
}

// ---------- K4.5: per-batch tables (colnorms from pp partials) ----------
__global__ void k45_tbl(const float* __restrict__ pp,
                        const float* __restrict__ cnt, const float* __restrict__ E,
                        float* __restrict__ tbl)
{
    int blk = blockIdx.x, t = threadIdx.x;
    if (blk < 32) {
        int b = blk >> 3, sj = blk & 7, stv = sj >> 2, j = sj & 3;
        float s = 0.f;
#pragma unroll
        for (int u = 0; u < 4; ++u) {
            int c = t * 4 + u;
            float xx = 0.f;
#pragma unroll
            for (int D = 0; D < 7; ++D)
                xx += pp[stv * 28672 + ((b * 7 + D) * 256 + c) * 4 + j];
            s += xx * xx;
        }
        s = wred(s);
        if (t == 0) tbl[b * 32 + stv * 4 + j] = sqrtf(s);
    } else if (t < 16) {
        int b = t >> 2, i = t & 3;
        tbl[b * 32 + 8 + 0 * 4 + i] = cnt[b * 4 + i] + 1e-6f;
        tbl[b * 32 + 8 + 1 * 4 + i] = cnt[b * 4 + (i ^ 2)] + 1e-6f;
        tbl[b * 32 + 8 + 2 * 4 + i] = cnt[b * 4 + (i ^ 3)] + 1.0f;
        tbl[b * 32 + 20 + 0 * 4 + i] = E[b * 16 + i * 4 + (i ^ 1)] + 1e-6f;
        tbl[b * 32 + 20 + 1 * 4 + i] = E[b * 16 + 5 * (i ^ 2)] + 1e-6f;
        tbl[b * 32 + 20 + 2 * 4 + i] = E[b * 16 + 5 * (i ^ 3)] + 1.0f;
    }
}

// ---------- K5: cosines + squared diff ----------
__global__ __launch_bounds__(256) void k5_final(
    const int* __restrict__ cls_arr, const float* __restrict__ w_arr,
    const float* __restrict__ n2S, const float* __restrict__ n2T,
    const float* __restrict__ dotS, const float* __restrict__ dotT,
    const float* __restrict__ tbl, double* __restrict__ partial_res)
{
    __shared__ double s4[4];
    int blk = blockIdx.x;
    int b = blk / 100, r = blk - b * 100;
    int t = threadIdx.x;
    int pq = b * HW + r * 256 + t;

    int i = cls_arr[pq];
    float wv = w_arr[pq];
    float sqS = sqrtf(n2S[pq] + n2S[102400 + pq]);
    float sqT = sqrtf(n2T[pq] + n2T[102400 + pq]);
    float4 dSa = *(const float4*)(dotS + (size_t)pq * 4);
    float4 dSb = *(const float4*)(dotS + 409600 + (size_t)pq * 4);
    float4 dTa = *(const float4*)(dotT + (size_t)pq * 4);
    float4 dTb = *(const float4*)(dotT + 409600 + (size_t)pq * 4);
    float4 dS = {dSa.x + dSb.x, dSa.y + dSb.y, dSa.z + dSb.z, dSa.w + dSb.w};
    float4 dT = {dTa.x + dTb.x, dTa.y + dTb.y, dTa.z + dTb.z, dTa.w + dTb.w};
    const float* tb = tbl + b * 32;

    double acc = 0.0;
#pragma unroll
    for (int v = 0; v < 3; ++v) {
        int j = i ^ (v + 1);
        float dsj = (j == 0) ? dS.x : (j == 1) ? dS.y : (j == 2) ? dS.z : dS.w;
        float dtj = (j == 0) ? dT.x : (j == 1) ? dT.y : (j == 2) ? dT.z : dT.w;
        float cnS = tb[j], cnT = tb[4 + j];
        float denS = tb[8 + v * 4 + i], denT = tb[20 + v * 4 + i];
        float cs = (dsj / denS) / fmaxf(sqS * (cnS / denS), 1e-8f);
        float ct = (dtj / denT) / fmaxf(sqT * (cnT / denT), 1e-8f);
        float vs = wv * cs, vt = wv * ct;
        float d = vs - vt;
        acc += (double)d * (double)d;
    }
    double tot = blockReduce256D(acc, s4);
    if (t == 0) partial_res[blk] = tot;
}

// ---------- K6: parallel final sum ----------
__global__ __launch_bounds__(256) void k6_out(const double* __restrict__ partial_res,
                                              float* __restrict__ out)
{
    __shared__ double s4[4];
    int t = threadIdx.x;
    double v = (t < 200) ? (partial_res[t] + partial_res[t + 200]) : 0.0;
    double tot = blockReduce256D(v, s4);
    if (t == 0) out[0] = (float)(tot / 307200.0);
}

// ---------- launch ----------
extern "C" void kernel_launch(void* const* d_in, const int* in_sizes, int n_in,
                              void* d_out, int out_size, void* d_ws, size_t ws_size,
                              hipStream_t stream)
{
    const float* feat_S  = (const float*)d_in[0];
    const float* feat_T  = (const float*)d_in[1];
    const float* Pred_S  = (const float*)d_in[2];
    const float* Pred_T  = (const float*)d_in[3];
    const float* S_atten = (const float*)d_in[4];
    const float* T_atten = (const float*)d_in[5];
    const int*   target  = (const int*)d_in[6];

    float* ws = (float*)d_ws;
    // non-overlapping layout (float offsets)
    unsigned short* featP = (unsigned short*)d_ws;            // 2 sides x 26,214,400 shorts -> [0, 26214400) floats
    unsigned short* WbfS  = (unsigned short*)(ws + 26214400); // [26214400, 26419200)
    unsigned short* WbfT  = (unsigned short*)(ws + 26419200); // [26419200, 26624000)
    int*   cls_a = (int*)(ws + 26624000);    // [26624000, 26726400)
    float* wT_a  = ws + 26726400;            // [26726400, 26828800)
    float* w_a   = ws + 26828800;            // [26828800, 26931200)
    float* n2S   = ws + 26939392;            // [26939392, 27144192)
    float* n2T   = ws + 27144192;            // [27144192, 27348992)
    float* dotS  = ws + 27348992;            // [27348992, 28168192)
    float* dotT  = ws + 28168192;            // [28168192, 28987392)
    float* pprep = ws + 28987392;            // [28987392, 28995392)
    float* cnt   = ws + 28995392;            // 16
    float* E     = ws + 28995408;            // 64
    float* tbl   = ws + 28995472;            // 128
    double* pres = (double*)(ws + 28995600); // 400 doubles = [28995600, 28996400)
    float* ppart = ws + 28996400;            // 57344 -> ends 29053744 (116.2 MB)

    k1_prep<<<400, 256, 0, stream>>>(Pred_S, Pred_T, target, cls_a, wT_a, w_a, pprep);
    k2_w<<<1104, 128, 0, stream>>>(S_atten, T_atten, cls_a, wT_a, WbfS, WbfT, pprep, cnt, E);
    k3_scan<<<3584, 256, 0, stream>>>(feat_S, feat_T, WbfS, WbfT, featP, ppart);
    k4_mfma<<<1024, 256, 0, stream>>>(featP, S_atten, T_atten, ppart, n2S, n2T, dotS, dotT);
    k45_tbl<<<33, 64, 0, stream>>>(ppart, cnt, E, tbl);
    k5_final<<<400, 256, 0, stream>>>(cls_a, w_a, n2S, n2T, dotS, dotT, tbl, pres);
    k6_out<<<1, 256, 0, stream>>>(pres, (float*)d_out);
}